// Round 11
// baseline (1655.220 us; speedup 1.0000x reference)
//
#include <hip/hip_runtime.h>
#include <stdint.h>

#define B_  8
#define N_  256
#define DH_ 192
#define L_  2
#define G3  576
#define G6  1152
#define NW  4      // WGs per batch per role
#define DS  48     // d-slice per WG
#define KD  24     // H-history dwords per WG (48 bf16)
#define GC  288    // g-cols per WG
#define MPSZ (8 * NW * DH_ * 3)   // MPs entries per parity per role
#define KDSZ (8 * NW)             // Kd entries per parity per role
#define STH 10001  // H1 channel stamp base
#define STP 20001  // PRE channel stamp base
#define SPK 50000  // prepack done
#define SF1 50001  // fc1 done
#define SF2 50002  // PRE done
#define SDN 60001  // scan done

typedef unsigned long long u64;

__device__ __forceinline__ float bflo(uint32_t u) { return __uint_as_float(u << 16); }
__device__ __forceinline__ float bfhi(uint32_t u) { return __uint_as_float(u & 0xffff0000u); }
__device__ __forceinline__ uint32_t f2bf(float f) {
    uint32_t x = __float_as_uint(f);
    x += 0x7fffu + ((x >> 16) & 1u);          // RNE
    return x >> 16;
}
__device__ __forceinline__ float sigm(float x)  { return 1.f / (1.f + __expf(-x)); }
__device__ __forceinline__ float tanhf_(float x){ return 1.f - 2.f / (1.f + __expf(2.f * x)); }
__device__ __forceinline__ u64 packvs(float v, int st) {
    return ((u64)(uint32_t)st << 32) | __float_as_uint(v);
}
__device__ __forceinline__ u64 agload(const u64* p) {
    return __hip_atomic_load(p, __ATOMIC_RELAXED, __HIP_MEMORY_SCOPE_AGENT);
}
__device__ __forceinline__ void agstore(u64* p, u64 v) {
    __hip_atomic_store(p, v, __ATOMIC_RELAXED, __HIP_MEMORY_SCOPE_AGENT);
}
__device__ __forceinline__ float u2f(u64 v) { return __uint_as_float((uint32_t)v); }

// Workgroup barrier WITHOUT the global-store drain (round-7 verified win).
__device__ __forceinline__ void wg_barrier() {
    asm volatile("s_waitcnt lgkmcnt(0)" ::: "memory");
    __builtin_amdgcn_s_barrier();
    asm volatile("" ::: "memory");
}

// ---------------------------------------------------------------------------
// LDS layouts (round-7 skeleton)
// ---------------------------------------------------------------------------
struct ScanSm {
    uint4 Wr4s[12 * DH_];            // 36,864 B (Wr stays in LDS)
    float sA0[2][N_], sA1[2][N_], sKsc[N_];
    float sAdjN[N_], sSmN[N_];
    float sPre[6 * DS], sXv[DS];
    float sM[DH_], su0[DS], su1[DS], sGc[GC], sHn[DS];
    float sRl[DH_], sP0l[DH_], sP1l[DH_];
    float sRedS[2][8], sSaved[8], sSavedA[2], sSavedS[2];
};
struct WorkSm {
    float sX[DH_];
    float sPv[GC];
};
struct PrologSm {
    float sA[8][768];
    float sRed[3][8][192];
};
struct MlpSm {
    float sH[8][576];
    float sRed[3][8][192];
    float sT[8][192];
};
union SmemAll { ScanSm s; WorkSm w; PrologSm p; MlpSm m; };

// ---------------------------------------------------------------------------
// Prepack slice (identical to round 3/7).
// ---------------------------------------------------------------------------
__device__ void prepack_slice(int idx,
    const float* __restrict__ wr0, const float* __restrict__ wr1,
    const float* __restrict__ c_wih, const float* __restrict__ c_whh,
    const float* __restrict__ c_bih, const float* __restrict__ c_bhh,
    const float* __restrict__ p_wih, const float* __restrict__ p_whh,
    const float* __restrict__ p_bih, const float* __restrict__ p_bhh,
    float* __restrict__ WpreT, uint32_t* __restrict__ W4,
    uint32_t* __restrict__ Wr4, uint32_t* __restrict__ Wp4w,
    float* __restrict__ biasPre, float* __restrict__ gbx)
{
    for (int l = 0; l < L_; ++l) {
        const float* cwih = c_wih + l * G3 * DH_;
        const float* cwhh = c_whh + l * G3 * DH_;
        const float* pwih = p_wih + l * G3 * DH_;
        const float* pwhh = p_whh + l * G3 * DH_;
        if (l == 0) {
            int k = idx / G6, r = idx - k * G6;
            float w = (r < G3) ? cwih[r * DH_ + k] : pwhh[(r - G3) * DH_ + k];
            WpreT[k * G6 + r] = w;
        }
        if (idx < NW * 27648) {
            int w = idx / 27648, pos = idx % 27648;
            int p4 = pos / 1152, rem = pos % 1152;
            int c2 = rem >> 2, s = rem & 3;
            int p = 4 * p4 + s;
            int j = c2 / DS, dd = c2 % DS;
            int c = 192 * j + DS * w + dd;
            float w0 = (c < G3) ? cwhh[c * DH_ + 2 * p]     : pwih[(c - G3) * DH_ + 2 * p];
            float w1 = (c < G3) ? cwhh[c * DH_ + 2 * p + 1] : pwih[(c - G3) * DH_ + 2 * p + 1];
            W4[l * NW * 27648 + idx] = f2bf(w0) | (f2bf(w1) << 16);
            if (l == 1) {
                int r = c;
                float v0 = (r < G3) ? cwih[r * DH_ + 2 * p]     : pwhh[(r - G3) * DH_ + 2 * p];
                float v1 = (r < G3) ? cwih[r * DH_ + 2 * p + 1] : pwhh[(r - G3) * DH_ + 2 * p + 1];
                Wp4w[idx] = f2bf(v0) | (f2bf(v1) << 16);
            }
        }
        if (idx < NW * 9216) {
            int w = idx / 9216, pos = idx % 9216;
            int kq = pos / 768, rem = pos % 768;
            int d = rem >> 2, s = rem & 3;
            int k = DS * w + 4 * kq + s;
            Wr4[l * NW * 9216 + idx] =
                f2bf(wr0[l * DH_ * DH_ + d * DH_ + k]) |
                (f2bf(wr1[l * DH_ * DH_ + d * DH_ + k]) << 16);
        }
        if (idx < G6) {
            float base = (idx < G3) ? c_bih[l * G3 + idx] : p_bhh[l * G3 + idx - G3];
            float fold = 0.f;
            if (idx < 384)                    fold = c_bhh[l * G3 + idx];
            else if (idx >= G3 && idx < 960)  fold = p_bih[l * G3 + idx - G3];
            biasPre[l * G6 + idx] = base + fold;
        }
        if (idx < 384) {
            gbx[l * 384 + idx] = (idx < DH_) ? c_bhh[l * G3 + 384 + idx]
                                             : p_bih[l * G3 + 384 + (idx - DH_)];
        }
    }
}

// ---------------------------------------------------------------------------
// Global sync among the 96 co-resident WGs via stamped flags.
// ---------------------------------------------------------------------------
__device__ void flag_sync(u64* flags, int wgid, int t, int stamp)
{
    __threadfence();
    __syncthreads();
    if (t == 0) agstore(&flags[wgid], packvs(0.f, stamp));
    if (t < 96) {
        while ((uint32_t)(agload(&flags[t]) >> 32) != (uint32_t)stamp) {}
    }
    __syncthreads();
    __threadfence();
    __syncthreads();
}

// ---------------------------------------------------------------------------
// Prologue: fc1 then PRE-l1. Identical to round 7.
// ---------------------------------------------------------------------------
__device__ void prologue(char* smem, int wgid, int t,
    const float* __restrict__ features, const float* __restrict__ fc1_w,
    const float* __restrict__ fc1_b, const float* __restrict__ WpreT,
    const float* __restrict__ biasPre,
    float* __restrict__ Hcat, float* __restrict__ PREg, u64* __restrict__ Fp)
{
    PrologSm* P = (PrologSm*)smem;
    const int c = t % 192, kg = t / 192;
    for (int tt = wgid; tt < 256; tt += 96) {
        const int r0 = tt * 8;
        for (int q = t; q < 1536; q += 576) {
            int r = q / 192, c4 = q % 192;
            *(float4*)&P->sA[r][4 * c4] = *(const float4*)(features + (size_t)(r0 + r) * 768 + 4 * c4);
        }
        __syncthreads();
        {
            const float* bp = fc1_w + (size_t)(kg * 256) * 192 + c;
            float acc[8] = {0.f, 0.f, 0.f, 0.f, 0.f, 0.f, 0.f, 0.f};
            #pragma unroll 8
            for (int kk = 0; kk < 256; ++kk) {
                float bv = bp[(size_t)kk * 192];
                #pragma unroll
                for (int rr = 0; rr < 8; ++rr) acc[rr] += P->sA[rr][kg * 256 + kk] * bv;
            }
            #pragma unroll
            for (int rr = 0; rr < 8; ++rr) P->sRed[kg][rr][c] = acc[rr];
        }
        __syncthreads();
        if (t < 192) {
            float bv = fc1_b[t];
            #pragma unroll
            for (int rr = 0; rr < 8; ++rr) {
                float v = P->sRed[0][rr][t] + P->sRed[1][rr][t] + P->sRed[2][rr][t] + bv;
                Hcat[(size_t)(r0 + rr) * G3 + t] = fmaxf(v, 0.f);
            }
        }
        __syncthreads();
    }
    flag_sync(Fp + 96, wgid, t, SF1);
    {
        const float bpa = biasPre[t], bpb = biasPre[576 + t];
        for (int tt = wgid; tt < 256; tt += 96) {
            const int r0 = tt * 8;
            for (int q = t; q < 384; q += 576) {
                int r = q / 48, c4 = q % 48;
                *(float4*)&P->sA[r][4 * c4] = *(const float4*)(Hcat + (size_t)(r0 + r) * G3 + 4 * c4);
            }
            __syncthreads();
            {
                const float* b0 = WpreT + t;
                float a0[8] = {0.f,0.f,0.f,0.f,0.f,0.f,0.f,0.f};
                float a1[8] = {0.f,0.f,0.f,0.f,0.f,0.f,0.f,0.f};
                #pragma unroll 4
                for (int k = 0; k < 192; ++k) {
                    float bva = b0[(size_t)k * G6];
                    float bvb = b0[(size_t)k * G6 + 576];
                    #pragma unroll
                    for (int rr = 0; rr < 8; ++rr) {
                        float av = P->sA[rr][k];
                        a0[rr] += av * bva; a1[rr] += av * bvb;
                    }
                }
                #pragma unroll
                for (int rr = 0; rr < 8; ++rr) {
                    PREg[(size_t)(r0 + rr) * G6 + t]       = a0[rr] + bpa;
                    PREg[(size_t)(r0 + rr) * G6 + 576 + t] = a1[rr] + bpb;
                }
            }
            __syncthreads();
        }
    }
    flag_sync(Fp + 192, wgid, t, SF2);
}

// ---------------------------------------------------------------------------
// Epilogue: 3-layer MLP head. Identical to round 7.
// ---------------------------------------------------------------------------
__device__ void mlp_tail(char* smem, int wgid, int t,
    const float* __restrict__ Hcat,
    const float* __restrict__ mw0, const float* __restrict__ mb0,
    const float* __restrict__ mw1, const float* __restrict__ mb1,
    const float* __restrict__ mw2, const float* __restrict__ mb2,
    float* __restrict__ out, u64* __restrict__ Fd)
{
    if (t < 64) {
        while ((uint32_t)(agload(&Fd[t]) >> 32) != (uint32_t)SDN)
            __builtin_amdgcn_s_sleep(2);
    }
    __syncthreads();
    __threadfence();
    __syncthreads();
    MlpSm* M = (MlpSm*)smem;
    const int c = t % 192, kg = t / 192;
    for (int tt = wgid; tt < 256; tt += 96) {
        const int r0 = tt * 8;
        for (int q = t; q < 1152; q += 576) {
            int r = q / 144, c4 = q % 144;
            *(float4*)&M->sH[r][4 * c4] = *(const float4*)(Hcat + (size_t)(r0 + r) * G3 + 4 * c4);
        }
        __syncthreads();
        {
            const float* bp = mw0 + (size_t)(kg * 192) * 192 + c;
            float acc[8] = {0.f,0.f,0.f,0.f,0.f,0.f,0.f,0.f};
            #pragma unroll 8
            for (int kk = 0; kk < 192; ++kk) {
                float bv = bp[(size_t)kk * 192];
                #pragma unroll
                for (int rr = 0; rr < 8; ++rr) acc[rr] += M->sH[rr][kg * 192 + kk] * bv;
            }
            #pragma unroll
            for (int rr = 0; rr < 8; ++rr) M->sRed[kg][rr][c] = acc[rr];
        }
        __syncthreads();
        if (t < 192) {
            float bv = mb0[t];
            #pragma unroll
            for (int rr = 0; rr < 8; ++rr)
                M->sT[rr][t] = fmaxf(M->sRed[0][rr][t] + M->sRed[1][rr][t] + M->sRed[2][rr][t] + bv, 0.f);
        }
        __syncthreads();
        {
            const float* bp = mw1 + (size_t)(kg * 64) * 192 + c;
            float acc[8] = {0.f,0.f,0.f,0.f,0.f,0.f,0.f,0.f};
            #pragma unroll 8
            for (int kk = 0; kk < 64; ++kk) {
                float bv = bp[(size_t)kk * 192];
                #pragma unroll
                for (int rr = 0; rr < 8; ++rr) acc[rr] += M->sT[rr][kg * 64 + kk] * bv;
            }
            #pragma unroll
            for (int rr = 0; rr < 8; ++rr) M->sRed[kg][rr][c] = acc[rr];
        }
        __syncthreads();
        if (t < 192) {
            float bv = mb1[t];
            #pragma unroll
            for (int rr = 0; rr < 8; ++rr)
                M->sH[rr][t] = fmaxf(M->sRed[0][rr][t] + M->sRed[1][rr][t] + M->sRed[2][rr][t] + bv, 0.f);
        }
        __syncthreads();
        {
            const float* bp = mw2 + (size_t)(kg * 64) * 192 + c;
            float acc[8] = {0.f,0.f,0.f,0.f,0.f,0.f,0.f,0.f};
            #pragma unroll 8
            for (int kk = 0; kk < 64; ++kk) {
                float bv = bp[(size_t)kk * 192];
                #pragma unroll
                for (int rr = 0; rr < 8; ++rr) acc[rr] += M->sH[rr][kg * 64 + kk] * bv;
            }
            #pragma unroll
            for (int rr = 0; rr < 8; ++rr) M->sRed[kg][rr][c] = acc[rr];
        }
        __syncthreads();
        if (t < 192) {
            float bv = mb2[t];
            #pragma unroll
            for (int rr = 0; rr < 8; ++rr)
                out[(size_t)(r0 + rr) * 192 + t] =
                    M->sRed[0][rr][t] + M->sRed[1][rr][t] + M->sRed[2][rr][t] + bv;
        }
        __syncthreads();
    }
}

// ---------------------------------------------------------------------------
// Scan body — round-10 structure with phase P4 ELIMINATED (5 barriers/step):
//   - M-combine done by the P3 poll threads (inputs visible since B2)
//   - su append of j=i-1 folded into the U-matvec epilogue (P3)
//   - AsB row write moved to idle P6 threads (inputs stable B2..next-P2)
// ---------------------------------------------------------------------------
template<int ISL2>
__device__ void scan_body(
    ScanSm* S, int b, int w, int t,
    const float* __restrict__ xin, float* __restrict__ hout,
    const float* __restrict__ PREg, const float* __restrict__ adj,
    const float* __restrict__ smask,
    const uint32_t* __restrict__ W4l, const uint32_t* __restrict__ Wr4l,
    const float* __restrict__ gbxl, const float* __restrict__ gatwl,
    uint32_t* __restrict__ Hw, u64* __restrict__ MPsl, u64* __restrict__ Kdl,
    u64* __restrict__ HcW, const u64* __restrict__ HcR,
    const u64* __restrict__ PREcR,
    float* __restrict__ AsB, int sbase)
{
    const int lane = t & 63, wave = t >> 6;
    const int dg0 = w * DS;
    const float* adjB = adj   + (size_t)b * N_ * N_;
    const float* smB  = smask + (size_t)b * N_ * N_;
    const int fi = b * NW;
    const int cB4 = t >> 1, khB4 = t & 1;
    const int w1 = (w + 1) & 3, w2 = (w + 2) & 3, w3 = (w + 3) & 3;

    // Wr -> LDS; Gc weights -> registers
    {
        uint32_t* wr = (uint32_t*)S->Wr4s;
        for (int q = t; q < 9216; q += 576) wr[q] = Wr4l[q];
    }
    uint4 wreg[12];
    {
        const uint4* W4v = (const uint4*)W4l;
        #pragma unroll
        for (int p4 = 0; p4 < 12; ++p4) wreg[p4] = W4v[(12 * khB4 + p4) * GC + cB4];
    }
    float wkv = 0.f, g2b = 0.f, g5b = 0.f;
    if (t < DS) { wkv = gatwl[DH_ + dg0 + t]; g2b = gbxl[dg0 + t]; g5b = gbxl[DH_ + dg0 + t]; }
    if (t < N_) { S->sKsc[t] = 0.f; S->sA0[1][t] = 0.f; S->sA1[1][t] = 0.f; }
    if (t < DS) { S->su0[t] = 0.f; S->su1[t] = 0.f; }
    if (t < 8)  S->sRedS[1][t] = 0.f;
    if (w == 0 && t < N_) AsB[t] = 0.f;

    if (!ISL2) {
        if (t < DS) {
            const float* pre = PREg + (size_t)(b * N_) * G6 + dg0 + t;
            S->sPre[t] = pre[0]; S->sPre[DS + t] = pre[192]; S->sPre[2 * DS + t] = pre[384];
            S->sPre[3 * DS + t] = pre[576]; S->sPre[4 * DS + t] = pre[768]; S->sPre[5 * DS + t] = pre[960];
            S->sXv[t] = xin[(size_t)(b * N_) * G3 + dg0 + t];
        }
        for (int q = t; q < 128; q += 576) {
            if (q < 64)  *(float4*)&S->sAdjN[4 * q] = *(const float4*)(adjB + N_ + 4 * q);
            else { int q2 = q - 64; *(float4*)&S->sSmN[4 * q2] = *(const float4*)(smB + N_ + 4 * q2); }
        }
    } else {
        for (int q = t; q < 320; q += 576) {
            if (q < 64)       *(float4*)&S->sAdjN[4 * q] = *(const float4*)(adjB + N_ + 4 * q);
            else if (q < 128) { int q2 = q - 64;  *(float4*)&S->sSmN[4 * q2] = *(const float4*)(smB + N_ + 4 * q2); }
            else if (q < 176) {
                int d = q - 128;
                const u64* p = HcR + ((size_t)(b * N_) * NW + w) * DS + d;
                u64 v; do { v = agload(p); } while ((uint32_t)(v >> 32) != (uint32_t)STH);
                S->sXv[d] = __uint_as_float((uint32_t)v);
            } else {
                int qq = q - 176;
                const u64* p = PREcR + ((size_t)(b * N_) * NW + w) * 144 + qq;
                u64 v; do { v = agload(p); } while ((uint32_t)(v >> 32) != (uint32_t)STP);
                uint32_t pl = (uint32_t)v;
                S->sPre[2 * qq] = bflo(pl); S->sPre[2 * qq + 1] = bfhi(pl);
            }
        }
    }
    __syncthreads();
    // ---- step 0 (no attention) ----
    {
        float hn = 0.f;
        if (t < DS) {
            float xv = S->sXv[t];
            float r1 = sigm(S->sPre[t]), z1 = sigm(S->sPre[DS + t]);
            float n1 = tanhf_(S->sPre[2 * DS + t] + r1 * g2b);
            float Cv = (1.f - z1) * n1;
            float r2 = sigm(S->sPre[3 * DS + t]), z2 = sigm(S->sPre[4 * DS + t]);
            float n2 = tanhf_(g5b + r2 * S->sPre[5 * DS + t]);
            hn = Cv + (1.f - z2) * n2 + z2 * xv;
            S->sHn[t] = hn;
            hout[(size_t)(b * N_) * G3 + dg0 + t] = hn;
            if (!ISL2) HcW[((size_t)(b * N_) * NW + w) * DS + t] = packvs(hn, STH);
        }
        if (t == 0) { S->sSavedA[1] = S->sAdjN[0]; S->sSavedS[1] = S->sSmN[0]; }
        if (wave == 0) {
            float v = hn * wkv;
            #pragma unroll
            for (int o = 32; o; o >>= 1) v += __shfl_xor(v, o);
            if (lane == 0) { S->sSaved[6] = v; agstore(&Kdl[fi + w], packvs(v, sbase)); }  // parity 0
        }
    }
    __syncthreads();
    if (t < KD) Hw[(size_t)t * N_] = f2bf(S->sHn[2 * t]) | (f2bf(S->sHn[2 * t + 1]) << 16);
    __syncthreads();

    for (int i = 1; i < N_; ++i) {
        const int row = b * N_ + i;
        const int stamp = sbase + i;
        const int pp = i & 1, pn = pp ^ 1;

        // ---- P1: raw partials + stamped send; prefetch ----------------------
        if (t < DH_) {
            float rr = 0.f, p0 = 0.f, p1 = 0.f;
            #pragma unroll 4
            for (int kq = 0; kq < 12; ++kq) {
                uint4 wv = S->Wr4s[kq * DH_ + t];
                const int k0 = 4 * kq;
                float lo, hi;
                lo = bflo(wv.x); hi = bfhi(wv.x);
                rr = fmaf(S->su0[k0 + 0], lo, rr); rr = fmaf(S->su1[k0 + 0], hi, rr);
                p0 = fmaf(S->sHn[k0 + 0], lo, p0); p1 = fmaf(S->sHn[k0 + 0], hi, p1);
                lo = bflo(wv.y); hi = bfhi(wv.y);
                rr = fmaf(S->su0[k0 + 1], lo, rr); rr = fmaf(S->su1[k0 + 1], hi, rr);
                p0 = fmaf(S->sHn[k0 + 1], lo, p0); p1 = fmaf(S->sHn[k0 + 1], hi, p1);
                lo = bflo(wv.z); hi = bfhi(wv.z);
                rr = fmaf(S->su0[k0 + 2], lo, rr); rr = fmaf(S->su1[k0 + 2], hi, rr);
                p0 = fmaf(S->sHn[k0 + 2], lo, p0); p1 = fmaf(S->sHn[k0 + 2], hi, p1);
                lo = bflo(wv.w); hi = bfhi(wv.w);
                rr = fmaf(S->su0[k0 + 3], lo, rr); rr = fmaf(S->su1[k0 + 3], hi, rr);
                p0 = fmaf(S->sHn[k0 + 3], lo, p0); p1 = fmaf(S->sHn[k0 + 3], hi, p1);
            }
            S->sRl[t] = rr; S->sP0l[t] = p0; S->sP1l[t] = p1;
            u64* base = &MPsl[(size_t)pp * MPSZ + ((size_t)(fi + w) * DH_ + t) * 3];
            agstore(base + 0, packvs(rr, stamp));
            agstore(base + 1, packvs(p0, stamp));
            agstore(base + 2, packvs(p1, stamp));
        } else if (t >= 384) {
            const int u = t - 384;
            const int inx = (i + 1 < N_) ? i + 1 : N_ - 1;
            if (!ISL2) {
                for (int qq = u; qq < 212; qq += 192) {
                    if (qq < 64)
                        *(float4*)&S->sAdjN[4 * qq] = *(const float4*)(adjB + (size_t)inx * N_ + 4 * qq);
                    else if (qq < 128) { int q2 = qq - 64;
                        *(float4*)&S->sSmN[4 * q2] = *(const float4*)(smB + (size_t)inx * N_ + 4 * q2); }
                    else if (qq < 140) { int q2 = qq - 128;
                        *(float4*)&S->sXv[4 * q2] = *(const float4*)(xin + (size_t)row * G3 + dg0 + 4 * q2); }
                    else { int q2 = qq - 140; int g = q2 / 12, o = q2 - 12 * g;
                        *(float4*)&S->sPre[g * DS + 4 * o] =
                            *(const float4*)(PREg + (size_t)row * G6 + g * DH_ + dg0 + 4 * o); }
                }
            } else {
                for (int qq = u; qq < 320; qq += 192) {
                    if (qq < 64)
                        *(float4*)&S->sAdjN[4 * qq] = *(const float4*)(adjB + (size_t)inx * N_ + 4 * qq);
                    else if (qq < 128) { int q2 = qq - 64;
                        *(float4*)&S->sSmN[4 * q2] = *(const float4*)(smB + (size_t)inx * N_ + 4 * q2); }
                    else if (qq < 176) {
                        int d = qq - 128;
                        const u64* p = HcR + ((size_t)row * NW + w) * DS + d;
                        u64 v; do { v = agload(p); } while ((uint32_t)(v >> 32) != (uint32_t)(STH + i));
                        S->sXv[d] = __uint_as_float((uint32_t)v);
                    } else {
                        int q2 = qq - 176;
                        const u64* p = PREcR + ((size_t)row * NW + w) * 144 + q2;
                        u64 v; do { v = agload(p); } while ((uint32_t)(v >> 32) != (uint32_t)(STP + i));
                        uint32_t pl = (uint32_t)v;
                        S->sPre[2 * q2] = bflo(pl); S->sPre[2 * q2 + 1] = bfhi(pl);
                    }
                }
            }
        }
        wg_barrier();                                            // B1

        // ---- P2: E(i+1) weights (t<256, skipping i-1) || Kd poll+scalars ----
        if (t < N_) {
            float e = 0.f;
            if (t == i) { S->sSavedA[pn] = S->sAdjN[t]; S->sSavedS[pn] = S->sSmN[t]; }
            if (t < i - 1 && S->sAdjN[t] > 0.5f) e = __expf(S->sKsc[t]);
            if (t != i - 1) { S->sA0[pn][t] = e * S->sSmN[t]; S->sA1[pn][t] = e - e * S->sSmN[t]; }
            float ps = e;
            #pragma unroll
            for (int o = 32; o; o >>= 1) ps += __shfl_xor(ps, o);
            if (lane == 0) S->sRedS[pn][wave] = ps;
        } else if (t == 320) {
            const uint32_t ex2 = (uint32_t)(stamp - 1);
            const int kpar = (i - 1) & 1;
            u64 k0, k1, k2;
            u64* q1 = &Kdl[kpar * KDSZ + fi + w1];
            u64* q2 = &Kdl[kpar * KDSZ + fi + w2];
            u64* q3 = &Kdl[kpar * KDSZ + fi + w3];
            do {
                k0 = agload(q1); k1 = agload(q2); k2 = agload(q3);
            } while ((uint32_t)(k0 >> 32) != ex2 || (uint32_t)(k1 >> 32) != ex2 ||
                     (uint32_t)(k2 >> 32) != ex2);
            float kdot = S->sSaved[6] + u2f(k0) + u2f(k1) + u2f(k2);
            float adj1 = S->sSavedA[pp], sm1 = S->sSavedS[pp];
            float er = __expf(kdot);
            float e1 = (adj1 > 0.5f) ? er : 0.f;
            float Ssum = S->sRedS[pp][0] + S->sRedS[pp][1] + S->sRedS[pp][2]
                       + S->sRedS[pp][3] + S->sRedS[pp][4] + e1;
            S->sKsc[i - 1] = kdot;
            float invS = 1.f / Ssum;
            float e1c0 = e1 * sm1, e1c1 = e1 - e1c0;
            S->sSaved[2] = invS;
            S->sSaved[4] = e1c0; S->sSaved[5] = e1c1;
            S->sA0[pp][i - 1] = e1c0; S->sA1[pp][i - 1] = e1c1;
            // append j = i-1 term for query i+1 (sAdjN holds row i+1 now)
            float adjn = S->sAdjN[i - 1], smn = S->sSmN[i - 1];
            float en = (adjn > 0.5f) ? er : 0.f;
            float n0 = en * smn;
            S->sA0[pn][i - 1] = n0; S->sA1[pn][i - 1] = en - n0;
            S->sRedS[pn][4] = en;
        }
        wg_barrier();                                            // B2

        // ---- P3: U(i+1) matvec + folded su-append || MPs poll + M-combine ---
        if (t < 384) {
            const int ilim = i - 1;                              // j <= i-2
            const int kd = t >> 4, jp = t & 15;
            const uint32_t* hp = Hw + (size_t)kd * N_;
            float u0l = 0.f, u0h = 0.f, u1l = 0.f, u1h = 0.f;
            int j = jp;
            while (j + 48 < ilim) {
                uint32_t h0 = hp[j], h1 = hp[j + 16], h2 = hp[j + 32], h3 = hp[j + 48];
                float b0, b1;
                b0 = S->sA0[pn][j];      b1 = S->sA1[pn][j];
                u0l = fmaf(b0, bflo(h0), u0l); u0h = fmaf(b0, bfhi(h0), u0h);
                u1l = fmaf(b1, bflo(h0), u1l); u1h = fmaf(b1, bfhi(h0), u1h);
                b0 = S->sA0[pn][j + 16]; b1 = S->sA1[pn][j + 16];
                u0l = fmaf(b0, bflo(h1), u0l); u0h = fmaf(b0, bfhi(h1), u0h);
                u1l = fmaf(b1, bflo(h1), u1l); u1h = fmaf(b1, bfhi(h1), u1h);
                b0 = S->sA0[pn][j + 32]; b1 = S->sA1[pn][j + 32];
                u0l = fmaf(b0, bflo(h2), u0l); u0h = fmaf(b0, bfhi(h2), u0h);
                u1l = fmaf(b1, bflo(h2), u1l); u1h = fmaf(b1, bfhi(h2), u1h);
                b0 = S->sA0[pn][j + 48]; b1 = S->sA1[pn][j + 48];
                u0l = fmaf(b0, bflo(h3), u0l); u0h = fmaf(b0, bfhi(h3), u0h);
                u1l = fmaf(b1, bflo(h3), u1l); u1h = fmaf(b1, bfhi(h3), u1h);
                j += 64;
            }
            for (; j < ilim; j += 16) {
                uint32_t hv = hp[j];
                float b0 = S->sA0[pn][j], b1 = S->sA1[pn][j];
                u0l = fmaf(b0, bflo(hv), u0l); u0h = fmaf(b0, bfhi(hv), u0h);
                u1l = fmaf(b1, bflo(hv), u1l); u1h = fmaf(b1, bfhi(hv), u1h);
            }
            #pragma unroll
            for (int o = 1; o <= 8; o <<= 1) {
                u0l += __shfl_xor(u0l, o); u0h += __shfl_xor(u0h, o);
                u1l += __shfl_xor(u1l, o); u1h += __shfl_xor(u1h, o);
            }
            if (jp == 0) {
                const float a0 = S->sA0[pn][i - 1], a1 = S->sA1[pn][i - 1];
                S->su0[2 * kd]     = u0l + a0 * S->sHn[2 * kd];
                S->su0[2 * kd + 1] = u0h + a0 * S->sHn[2 * kd + 1];
                S->su1[2 * kd]     = u1l + a1 * S->sHn[2 * kd];
                S->su1[2 * kd + 1] = u1h + a1 * S->sHn[2 * kd + 1];
            }
        } else {
            const int d = t - 384;
            const u64* pA = &MPsl[(size_t)pp * MPSZ + ((size_t)(fi + w1) * DH_ + d) * 3];
            const u64* pB = &MPsl[(size_t)pp * MPSZ + ((size_t)(fi + w2) * DH_ + d) * 3];
            const u64* pC = &MPsl[(size_t)pp * MPSZ + ((size_t)(fi + w3) * DH_ + d) * 3];
            const uint32_t ex = (uint32_t)stamp;
            u64 a0, a1, a2, b0, b1, b2, c0, c1, c2;
            do {
                a0 = agload(pA); a1 = agload(pA + 1); a2 = agload(pA + 2);
                b0 = agload(pB); b1 = agload(pB + 1); b2 = agload(pB + 2);
                c0 = agload(pC); c1 = agload(pC + 1); c2 = agload(pC + 2);
            } while ((uint32_t)(a0 >> 32) != ex || (uint32_t)(a1 >> 32) != ex ||
                     (uint32_t)(a2 >> 32) != ex || (uint32_t)(b0 >> 32) != ex ||
                     (uint32_t)(b1 >> 32) != ex || (uint32_t)(b2 >> 32) != ex ||
                     (uint32_t)(c0 >> 32) != ex || (uint32_t)(c1 >> 32) != ex ||
                     (uint32_t)(c2 >> 32) != ex);
            const float rs  = S->sRl[d]  + u2f(a0) + u2f(b0) + u2f(c0);
            const float p0s = S->sP0l[d] + u2f(a1) + u2f(b1) + u2f(c1);
            const float p1s = S->sP1l[d] + u2f(a2) + u2f(b2) + u2f(c2);
            S->sM[d] = (rs + S->sSaved[4] * p0s + S->sSaved[5] * p1s) * S->sSaved[2];
        }
        wg_barrier();                                            // B3

        // ---- P5: Gc from register-resident weights --------------------------
        {
            float g = 0.f;
            #pragma unroll
            for (int p4 = 0; p4 < 12; ++p4) {
                const uint4 wv = wreg[p4];
                const int m0 = 8 * (12 * khB4 + p4);
                g = fmaf(S->sM[m0 + 0], bflo(wv.x), g); g = fmaf(S->sM[m0 + 1], bfhi(wv.x), g);
                g = fmaf(S->sM[m0 + 2], bflo(wv.y), g); g = fmaf(S->sM[m0 + 3], bfhi(wv.y), g);
                g = fmaf(S->sM[m0 + 4], bflo(wv.z), g); g = fmaf(S->sM[m0 + 5], bfhi(wv.z), g);
                g = fmaf(S->sM[m0 + 6], bflo(wv.w), g); g = fmaf(S->sM[m0 + 7], bfhi(wv.w), g);
            }
            g += __shfl_xor(g, 1);
            if (khB4 == 0) S->sGc[cB4] = g;
        }
        wg_barrier();                                            // B5

        // ---- P6: gates -> hn(i); Hc; Kd; Hw pack; AsB row i -----------------
        {
            float hn = 0.f;
            if (t < DS) {
                float Mv = S->sM[dg0 + t];
                float r1 = sigm(S->sPre[t] + S->sGc[t]);
                float z1 = sigm(S->sPre[DS + t] + S->sGc[DS + t]);
                float n1 = tanhf_(S->sPre[2 * DS + t] + r1 * (S->sGc[2 * DS + t] + g2b));
                float Cv = (1.f - z1) * n1 + z1 * Mv;
                float r2 = sigm(S->sGc[3 * DS + t] + S->sPre[3 * DS + t]);
                float z2 = sigm(S->sGc[4 * DS + t] + S->sPre[4 * DS + t]);
                float n2 = tanhf_(S->sGc[5 * DS + t] + g5b + r2 * S->sPre[5 * DS + t]);
                hn = Cv + (1.f - z2) * n2 + z2 * S->sXv[t];
                S->sHn[t] = hn;
                hout[(size_t)row * G3 + dg0 + t] = hn;
                if (!ISL2) HcW[((size_t)row * NW + w) * DS + t] = packvs(hn, STH + i);
            }
            if (wave == 0) {
                float v = hn * wkv;
                #pragma unroll
                for (int o = 32; o; o >>= 1) v += __shfl_xor(v, o);
                if (lane == 0) { S->sSaved[6] = v; agstore(&Kdl[pp * KDSZ + fi + w], packvs(v, stamp)); }
            } else if (w == 0 && t >= 64 && t < 320) {
                const int j = t - 64;
                AsB[(size_t)i * N_ + j] = (S->sA0[pp][j] + S->sA1[pp][j]) * S->sSaved[2];
            }
            if (t < KD) Hw[(size_t)t * N_ + i] = f2bf(S->sHn[2 * t]) | (f2bf(S->sHn[2 * t + 1]) << 16);
        }
        wg_barrier();                                            // B6
    }
}

// ---------------------------------------------------------------------------
// PRE worker — identical to round 7.
// ---------------------------------------------------------------------------
__device__ void worker_body(WorkSm* Wm, int b, int w, int t,
    const uint32_t* __restrict__ Wp4g, const float* __restrict__ bias2,
    const u64* __restrict__ HcR, u64* __restrict__ PREcW)
{
    const int c = t >> 1, kh = t & 1;
    uint4 wpreg[12];
    {
        const uint4* v4 = (const uint4*)Wp4g;
        #pragma unroll
        for (int p4 = 0; p4 < 12; ++p4) wpreg[p4] = v4[(12 * kh + p4) * GC + c];
    }
    float bv = 0.f;
    if (kh == 0) bv = bias2[192 * (c / DS) + w * DS + (c % DS)];
    for (int i = 0; i < N_; ++i) {
        if (t < DH_) {
            const u64* p = HcR + ((size_t)(b * N_ + i) * NW + (t / DS)) * DS + (t % DS);
            u64 v; do { v = agload(p); } while ((uint32_t)(v >> 32) != (uint32_t)(STH + i));
            Wm->sX[t] = __uint_as_float((uint32_t)v);
        }
        wg_barrier();
        {
            float g = 0.f;
            #pragma unroll
            for (int p4 = 0; p4 < 12; ++p4) {
                const uint4 wv = wpreg[p4];
                const int m0 = 8 * (12 * kh + p4);
                g = fmaf(Wm->sX[m0 + 0], bflo(wv.x), g); g = fmaf(Wm->sX[m0 + 1], bfhi(wv.x), g);
                g = fmaf(Wm->sX[m0 + 2], bflo(wv.y), g); g = fmaf(Wm->sX[m0 + 3], bfhi(wv.y), g);
                g = fmaf(Wm->sX[m0 + 4], bflo(wv.z), g); g = fmaf(Wm->sX[m0 + 5], bfhi(wv.z), g);
                g = fmaf(Wm->sX[m0 + 6], bflo(wv.w), g); g = fmaf(Wm->sX[m0 + 7], bfhi(wv.w), g);
            }
            g += __shfl_xor(g, 1);
            if (kh == 0) Wm->sPv[c] = g + bv;
        }
        wg_barrier();
        if (t < 144) {
            u64 v = ((u64)(uint32_t)(STP + i) << 32)
                  | f2bf(Wm->sPv[2 * t]) | (f2bf(Wm->sPv[2 * t + 1]) << 16);
            agstore(&PREcW[((size_t)(b * N_ + i) * NW + w) * 144 + t], v);
        }
        wg_barrier();
    }
}

// ---------------------------------------------------------------------------
// Single fused kernel.
// ---------------------------------------------------------------------------
__global__ __launch_bounds__(576, 1) void pipeline_kernel(
    const float* __restrict__ features, const float* __restrict__ fc1_w,
    const float* __restrict__ fc1_b,
    const float* __restrict__ adj, const float* __restrict__ smask,
    const float* __restrict__ gatw,
    const float* __restrict__ wr0, const float* __restrict__ wr1,
    const float* __restrict__ c_wih, const float* __restrict__ c_whh,
    const float* __restrict__ c_bih, const float* __restrict__ c_bhh,
    const float* __restrict__ p_wih, const float* __restrict__ p_whh,
    const float* __restrict__ p_bih, const float* __restrict__ p_bhh,
    const float* __restrict__ mw0, const float* __restrict__ mb0,
    const float* __restrict__ mw1, const float* __restrict__ mb1,
    const float* __restrict__ mw2, const float* __restrict__ mb2,
    float* __restrict__ Hcat, float* __restrict__ PREg,
    float* __restrict__ WpreT, uint32_t* __restrict__ W4,
    uint32_t* __restrict__ Wr4, uint32_t* __restrict__ Wp4w,
    float* __restrict__ biasPre, float* __restrict__ gbx,
    uint32_t* __restrict__ Hb, u64* __restrict__ MPs, u64* __restrict__ Kd,
    u64* __restrict__ Hc, u64* __restrict__ PREc,
    u64* __restrict__ Fp, u64* __restrict__ Fd,
    float* __restrict__ out)
{
    __shared__ __align__(16) char smem[sizeof(SmemAll)];
    const int blk = blockIdx.x, t = threadIdx.x;
    const int wgid = blk;
    const int b = blk & 7, r12 = blk >> 3;
    const int role = r12 >> 2, w = r12 & 3;

    // ---- prepack slices (all WGs) ------------------------------------------
    for (int j = 0; j < 4; ++j) {
        int idx = wgid * 576 + t + 55296 * j;
        prepack_slice(idx, wr0, wr1, c_wih, c_whh, c_bih, c_bhh,
                      p_wih, p_whh, p_bih, p_bhh,
                      WpreT, W4, Wr4, Wp4w, biasPre, gbx);
    }
    flag_sync(Fp, wgid, t, SPK);

    // ---- fc1 + PRE-l1 prologue ---------------------------------------------
    prologue(smem, wgid, t, features, fc1_w, fc1_b, WpreT, biasPre,
             Hcat, PREg, Fp);

    // ---- roles -------------------------------------------------------------
    float* As = out + 393216;
    if (role == 0) {
        scan_body<0>((ScanSm*)smem, b, w, t,
            Hcat, Hcat + 192, PREg, adj, smask,
            W4, Wr4, gbx, gatw,
            Hb + (size_t)(b * NW + w) * KD * N_, MPs, Kd,
            Hc, nullptr, nullptr,
            As + (size_t)b * (L_ * N_ * N_), 1);
        __threadfence();
        __syncthreads();
        if (t == 0) agstore(&Fd[b * 8 + w], packvs(0.f, SDN));
    } else if (role == 2) {
        scan_body<1>((ScanSm*)smem, b, w, t,
            nullptr, Hcat + 384, nullptr, adj, smask,
            W4 + NW * 27648, Wr4 + NW * 9216, gbx + 384, gatw + 384,
            Hb + (size_t)(32 + b * NW + w) * KD * N_,
            MPs + (size_t)2 * MPSZ, Kd + 2 * KDSZ,
            nullptr, Hc, PREc,
            As + (size_t)b * (L_ * N_ * N_) + N_ * N_, 30001);
        __threadfence();
        __syncthreads();
        if (t == 0) agstore(&Fd[b * 8 + 4 + w], packvs(0.f, SDN));
    } else {
        worker_body((WorkSm*)smem, b, w, t,
            Wp4w + (size_t)w * 27648, biasPre + G6,
            Hc, PREc);
    }

    // ---- MLP epilogue (all WGs) --------------------------------------------
    mlp_tail(smem, wgid, t, Hcat, mw0, mb0, mw1, mb1, mw2, mb2, out, Fd);
}

// ---------------------------------------------------------------------------
extern "C" void kernel_launch(void* const* d_in, const int* in_sizes, int n_in,
                              void* d_out, int out_size, void* d_ws, size_t ws_size,
                              hipStream_t stream)
{
    const float* features = (const float*)d_in[0];
    const float* adj      = (const float*)d_in[1];
    const float* smask    = (const float*)d_in[2];
    const float* fc1_w = (const float*)d_in[5];
    const float* fc1_b = (const float*)d_in[6];
    const float* gat_w = (const float*)d_in[7];
    const float* wr0   = (const float*)d_in[9];
    const float* wr1   = (const float*)d_in[10];
    const float* c_wih = (const float*)d_in[11];
    const float* c_whh = (const float*)d_in[12];
    const float* c_bih = (const float*)d_in[13];
    const float* c_bhh = (const float*)d_in[14];
    const float* p_wih = (const float*)d_in[15];
    const float* p_whh = (const float*)d_in[16];
    const float* p_bih = (const float*)d_in[17];
    const float* p_bhh = (const float*)d_in[18];
    const float* mw0 = (const float*)d_in[19];
    const float* mb0 = (const float*)d_in[20];
    const float* mw1 = (const float*)d_in[21];
    const float* mb1 = (const float*)d_in[22];
    const float* mw2 = (const float*)d_in[23];
    const float* mb2 = (const float*)d_in[24];
    float* out = (float*)d_out;

    char* wsb = (char*)d_ws;
    size_t off = 0;
    auto carve = [&](size_t bytes) -> char* {
        char* p = wsb + off;
        off = (off + bytes + 255) & ~(size_t)255;
        return p;
    };
    float* Hcat     = (float*)carve(2048ull * 576 * 4);
    float* PREg     = (float*)carve(2048ull * 1152 * 4);
    float* WpreT    = (float*)carve(192ull * 1152 * 4);
    uint32_t* W4    = (uint32_t*)carve(2ull * NW * 27648 * 4);
    uint32_t* Wr4   = (uint32_t*)carve(2ull * NW * 9216 * 4);
    uint32_t* Wp4w  = (uint32_t*)carve((size_t)NW * 27648 * 4);
    float* biasPre  = (float*)carve(2ull * 1152 * 4);
    float* gbx      = (float*)carve(2ull * 384 * 4);
    uint32_t* Hb    = (uint32_t*)carve(64ull * KD * 256 * 4);
    u64* MPs        = (u64*)carve(4ull * MPSZ * 8);      // 2 roles x 2 parities
    u64* Kd         = (u64*)carve(4ull * KDSZ * 8);      // 2 roles x 2 parities
    u64* Hc         = (u64*)carve(8ull * 256 * NW * DS * 8);
    u64* PREc       = (u64*)carve(8ull * 256 * NW * 144 * 8);
    u64* Fp         = (u64*)carve(288ull * 8);
    u64* Fd         = (u64*)carve(64ull * 8);

    pipeline_kernel<<<dim3(96), 576, 0, stream>>>(
        features, fc1_w, fc1_b, adj, smask, gat_w,
        wr0, wr1, c_wih, c_whh, c_bih, c_bhh, p_wih, p_whh, p_bih, p_bhh,
        mw0, mb0, mw1, mb1, mw2, mb2,
        Hcat, PREg, WpreT, W4, Wr4, Wp4w, biasPre, gbx,
        Hb, MPs, Kd, Hc, PREc, Fp, Fd, out);
}

// Round 12
// 1629.354 us; speedup vs baseline: 1.0159x; 1.0159x over previous
//
#include <hip/hip_runtime.h>
#include <stdint.h>

#define B_  8
#define N_  256
#define DH_ 192
#define L_  2
#define G3  576
#define G6  1152
#define NW  4      // WGs per batch per role
#define DS  48     // d-slice per WG
#define KD  24     // H-history dwords per WG (48 bf16)
#define GC  288    // g-cols per WG
#define MPSZ (8 * NW * DH_ * 3)   // MPs entries per parity per role
#define KDSZ (8 * NW)             // Kd entries per parity per role
#define STH 10001  // H1 channel stamp base
#define STP 20001  // PRE channel stamp base
#define SPK 50000  // prepack done
#define SF1 50001  // fc1 done
#define SF2 50002  // PRE done
#define SDN 60001  // scan done

typedef unsigned long long u64;

__device__ __forceinline__ float bflo(uint32_t u) { return __uint_as_float(u << 16); }
__device__ __forceinline__ float bfhi(uint32_t u) { return __uint_as_float(u & 0xffff0000u); }
__device__ __forceinline__ uint32_t f2bf(float f) {
    uint32_t x = __float_as_uint(f);
    x += 0x7fffu + ((x >> 16) & 1u);          // RNE
    return x >> 16;
}
__device__ __forceinline__ float sigm(float x)  { return 1.f / (1.f + __expf(-x)); }
__device__ __forceinline__ float tanhf_(float x){ return 1.f - 2.f / (1.f + __expf(2.f * x)); }
__device__ __forceinline__ u64 packvs(float v, int st) {
    return ((u64)(uint32_t)st << 32) | __float_as_uint(v);
}
__device__ __forceinline__ u64 agload(const u64* p) {
    return __hip_atomic_load(p, __ATOMIC_RELAXED, __HIP_MEMORY_SCOPE_AGENT);
}
__device__ __forceinline__ void agstore(u64* p, u64 v) {
    __hip_atomic_store(p, v, __ATOMIC_RELAXED, __HIP_MEMORY_SCOPE_AGENT);
}
__device__ __forceinline__ float u2f(u64 v) { return __uint_as_float((uint32_t)v); }

// Workgroup barrier WITHOUT the global-store drain (round-7 verified win).
__device__ __forceinline__ void wg_barrier() {
    asm volatile("s_waitcnt lgkmcnt(0)" ::: "memory");
    __builtin_amdgcn_s_barrier();
    asm volatile("" ::: "memory");
}

// ---------------------------------------------------------------------------
// LDS layouts (round-7 skeleton)
// ---------------------------------------------------------------------------
struct ScanSm {
    uint4 Wr4s[12 * DH_];            // 36,864 B (Wr stays in LDS)
    float sA0[2][N_], sA1[2][N_], sKsc[N_];
    float sAdjN[N_], sSmN[N_];
    float sPre[6 * DS], sXv[DS];
    float sM[DH_], su0[DS], su1[DS], sGc[GC], sHn[DS];
    float sRl[DH_], sP0l[DH_], sP1l[DH_];
    float sRedS[2][8], sSaved[8], sSavedA[2], sSavedS[2];
};
struct WorkSm {
    float sX[DH_];
    float sPv[GC];
};
struct PrologSm {
    float sA[8][768];
    float sRed[3][8][192];
};
struct MlpSm {
    float sH[8][576];
    float sRed[3][8][192];
    float sT[8][192];
};
union SmemAll { ScanSm s; WorkSm w; PrologSm p; MlpSm m; };

// ---------------------------------------------------------------------------
// Prepack slice (identical to round 3/7).
// ---------------------------------------------------------------------------
__device__ void prepack_slice(int idx,
    const float* __restrict__ wr0, const float* __restrict__ wr1,
    const float* __restrict__ c_wih, const float* __restrict__ c_whh,
    const float* __restrict__ c_bih, const float* __restrict__ c_bhh,
    const float* __restrict__ p_wih, const float* __restrict__ p_whh,
    const float* __restrict__ p_bih, const float* __restrict__ p_bhh,
    float* __restrict__ WpreT, uint32_t* __restrict__ W4,
    uint32_t* __restrict__ Wr4, uint32_t* __restrict__ Wp4w,
    float* __restrict__ biasPre, float* __restrict__ gbx)
{
    for (int l = 0; l < L_; ++l) {
        const float* cwih = c_wih + l * G3 * DH_;
        const float* cwhh = c_whh + l * G3 * DH_;
        const float* pwih = p_wih + l * G3 * DH_;
        const float* pwhh = p_whh + l * G3 * DH_;
        if (l == 0) {
            int k = idx / G6, r = idx - k * G6;
            float w = (r < G3) ? cwih[r * DH_ + k] : pwhh[(r - G3) * DH_ + k];
            WpreT[k * G6 + r] = w;
        }
        if (idx < NW * 27648) {
            int w = idx / 27648, pos = idx % 27648;
            int p4 = pos / 1152, rem = pos % 1152;
            int c2 = rem >> 2, s = rem & 3;
            int p = 4 * p4 + s;
            int j = c2 / DS, dd = c2 % DS;
            int c = 192 * j + DS * w + dd;
            float w0 = (c < G3) ? cwhh[c * DH_ + 2 * p]     : pwih[(c - G3) * DH_ + 2 * p];
            float w1 = (c < G3) ? cwhh[c * DH_ + 2 * p + 1] : pwih[(c - G3) * DH_ + 2 * p + 1];
            W4[l * NW * 27648 + idx] = f2bf(w0) | (f2bf(w1) << 16);
            if (l == 1) {
                int r = c;
                float v0 = (r < G3) ? cwih[r * DH_ + 2 * p]     : pwhh[(r - G3) * DH_ + 2 * p];
                float v1 = (r < G3) ? cwih[r * DH_ + 2 * p + 1] : pwhh[(r - G3) * DH_ + 2 * p + 1];
                Wp4w[idx] = f2bf(v0) | (f2bf(v1) << 16);
            }
        }
        if (idx < NW * 9216) {
            int w = idx / 9216, pos = idx % 9216;
            int kq = pos / 768, rem = pos % 768;
            int d = rem >> 2, s = rem & 3;
            int k = DS * w + 4 * kq + s;
            Wr4[l * NW * 9216 + idx] =
                f2bf(wr0[l * DH_ * DH_ + d * DH_ + k]) |
                (f2bf(wr1[l * DH_ * DH_ + d * DH_ + k]) << 16);
        }
        if (idx < G6) {
            float base = (idx < G3) ? c_bih[l * G3 + idx] : p_bhh[l * G3 + idx - G3];
            float fold = 0.f;
            if (idx < 384)                    fold = c_bhh[l * G3 + idx];
            else if (idx >= G3 && idx < 960)  fold = p_bih[l * G3 + idx - G3];
            biasPre[l * G6 + idx] = base + fold;
        }
        if (idx < 384) {
            gbx[l * 384 + idx] = (idx < DH_) ? c_bhh[l * G3 + 384 + idx]
                                             : p_bih[l * G3 + 384 + (idx - DH_)];
        }
    }
}

// ---------------------------------------------------------------------------
// Global sync among the 96 co-resident WGs via stamped flags.
// ---------------------------------------------------------------------------
__device__ void flag_sync(u64* flags, int wgid, int t, int stamp)
{
    __threadfence();
    __syncthreads();
    if (t == 0) agstore(&flags[wgid], packvs(0.f, stamp));
    if (t < 96) {
        while ((uint32_t)(agload(&flags[t]) >> 32) != (uint32_t)stamp) {}
    }
    __syncthreads();
    __threadfence();
    __syncthreads();
}

// ---------------------------------------------------------------------------
// Prologue: fc1 then PRE-l1. Identical to round 7.
// ---------------------------------------------------------------------------
__device__ void prologue(char* smem, int wgid, int t,
    const float* __restrict__ features, const float* __restrict__ fc1_w,
    const float* __restrict__ fc1_b, const float* __restrict__ WpreT,
    const float* __restrict__ biasPre,
    float* __restrict__ Hcat, float* __restrict__ PREg, u64* __restrict__ Fp)
{
    PrologSm* P = (PrologSm*)smem;
    const int c = t % 192, kg = t / 192;
    for (int tt = wgid; tt < 256; tt += 96) {
        const int r0 = tt * 8;
        for (int q = t; q < 1536; q += 576) {
            int r = q / 192, c4 = q % 192;
            *(float4*)&P->sA[r][4 * c4] = *(const float4*)(features + (size_t)(r0 + r) * 768 + 4 * c4);
        }
        __syncthreads();
        {
            const float* bp = fc1_w + (size_t)(kg * 256) * 192 + c;
            float acc[8] = {0.f, 0.f, 0.f, 0.f, 0.f, 0.f, 0.f, 0.f};
            #pragma unroll 8
            for (int kk = 0; kk < 256; ++kk) {
                float bv = bp[(size_t)kk * 192];
                #pragma unroll
                for (int rr = 0; rr < 8; ++rr) acc[rr] += P->sA[rr][kg * 256 + kk] * bv;
            }
            #pragma unroll
            for (int rr = 0; rr < 8; ++rr) P->sRed[kg][rr][c] = acc[rr];
        }
        __syncthreads();
        if (t < 192) {
            float bv = fc1_b[t];
            #pragma unroll
            for (int rr = 0; rr < 8; ++rr) {
                float v = P->sRed[0][rr][t] + P->sRed[1][rr][t] + P->sRed[2][rr][t] + bv;
                Hcat[(size_t)(r0 + rr) * G3 + t] = fmaxf(v, 0.f);
            }
        }
        __syncthreads();
    }
    flag_sync(Fp + 96, wgid, t, SF1);
    {
        const float bpa = biasPre[t], bpb = biasPre[576 + t];
        for (int tt = wgid; tt < 256; tt += 96) {
            const int r0 = tt * 8;
            for (int q = t; q < 384; q += 576) {
                int r = q / 48, c4 = q % 48;
                *(float4*)&P->sA[r][4 * c4] = *(const float4*)(Hcat + (size_t)(r0 + r) * G3 + 4 * c4);
            }
            __syncthreads();
            {
                const float* b0 = WpreT + t;
                float a0[8] = {0.f,0.f,0.f,0.f,0.f,0.f,0.f,0.f};
                float a1[8] = {0.f,0.f,0.f,0.f,0.f,0.f,0.f,0.f};
                #pragma unroll 4
                for (int k = 0; k < 192; ++k) {
                    float bva = b0[(size_t)k * G6];
                    float bvb = b0[(size_t)k * G6 + 576];
                    #pragma unroll
                    for (int rr = 0; rr < 8; ++rr) {
                        float av = P->sA[rr][k];
                        a0[rr] += av * bva; a1[rr] += av * bvb;
                    }
                }
                #pragma unroll
                for (int rr = 0; rr < 8; ++rr) {
                    PREg[(size_t)(r0 + rr) * G6 + t]       = a0[rr] + bpa;
                    PREg[(size_t)(r0 + rr) * G6 + 576 + t] = a1[rr] + bpb;
                }
            }
            __syncthreads();
        }
    }
    flag_sync(Fp + 192, wgid, t, SF2);
}

// ---------------------------------------------------------------------------
// Epilogue: 3-layer MLP head. Identical to round 7.
// ---------------------------------------------------------------------------
__device__ void mlp_tail(char* smem, int wgid, int t,
    const float* __restrict__ Hcat,
    const float* __restrict__ mw0, const float* __restrict__ mb0,
    const float* __restrict__ mw1, const float* __restrict__ mb1,
    const float* __restrict__ mw2, const float* __restrict__ mb2,
    float* __restrict__ out, u64* __restrict__ Fd)
{
    if (t < 64) {
        while ((uint32_t)(agload(&Fd[t]) >> 32) != (uint32_t)SDN)
            __builtin_amdgcn_s_sleep(2);
    }
    __syncthreads();
    __threadfence();
    __syncthreads();
    MlpSm* M = (MlpSm*)smem;
    const int c = t % 192, kg = t / 192;
    for (int tt = wgid; tt < 256; tt += 96) {
        const int r0 = tt * 8;
        for (int q = t; q < 1152; q += 576) {
            int r = q / 144, c4 = q % 144;
            *(float4*)&M->sH[r][4 * c4] = *(const float4*)(Hcat + (size_t)(r0 + r) * G3 + 4 * c4);
        }
        __syncthreads();
        {
            const float* bp = mw0 + (size_t)(kg * 192) * 192 + c;
            float acc[8] = {0.f,0.f,0.f,0.f,0.f,0.f,0.f,0.f};
            #pragma unroll 8
            for (int kk = 0; kk < 192; ++kk) {
                float bv = bp[(size_t)kk * 192];
                #pragma unroll
                for (int rr = 0; rr < 8; ++rr) acc[rr] += M->sH[rr][kg * 192 + kk] * bv;
            }
            #pragma unroll
            for (int rr = 0; rr < 8; ++rr) M->sRed[kg][rr][c] = acc[rr];
        }
        __syncthreads();
        if (t < 192) {
            float bv = mb0[t];
            #pragma unroll
            for (int rr = 0; rr < 8; ++rr)
                M->sT[rr][t] = fmaxf(M->sRed[0][rr][t] + M->sRed[1][rr][t] + M->sRed[2][rr][t] + bv, 0.f);
        }
        __syncthreads();
        {
            const float* bp = mw1 + (size_t)(kg * 64) * 192 + c;
            float acc[8] = {0.f,0.f,0.f,0.f,0.f,0.f,0.f,0.f};
            #pragma unroll 8
            for (int kk = 0; kk < 64; ++kk) {
                float bv = bp[(size_t)kk * 192];
                #pragma unroll
                for (int rr = 0; rr < 8; ++rr) acc[rr] += M->sT[rr][kg * 64 + kk] * bv;
            }
            #pragma unroll
            for (int rr = 0; rr < 8; ++rr) M->sRed[kg][rr][c] = acc[rr];
        }
        __syncthreads();
        if (t < 192) {
            float bv = mb1[t];
            #pragma unroll
            for (int rr = 0; rr < 8; ++rr)
                M->sH[rr][t] = fmaxf(M->sRed[0][rr][t] + M->sRed[1][rr][t] + M->sRed[2][rr][t] + bv, 0.f);
        }
        __syncthreads();
        {
            const float* bp = mw2 + (size_t)(kg * 64) * 192 + c;
            float acc[8] = {0.f,0.f,0.f,0.f,0.f,0.f,0.f,0.f};
            #pragma unroll 8
            for (int kk = 0; kk < 64; ++kk) {
                float bv = bp[(size_t)kk * 192];
                #pragma unroll
                for (int rr = 0; rr < 8; ++rr) acc[rr] += M->sH[rr][kg * 64 + kk] * bv;
            }
            #pragma unroll
            for (int rr = 0; rr < 8; ++rr) M->sRed[kg][rr][c] = acc[rr];
        }
        __syncthreads();
        if (t < 192) {
            float bv = mb2[t];
            #pragma unroll
            for (int rr = 0; rr < 8; ++rr)
                out[(size_t)(r0 + rr) * 192 + t] =
                    M->sRed[0][rr][t] + M->sRed[1][rr][t] + M->sRed[2][rr][t] + bv;
        }
        __syncthreads();
    }
}

// ---------------------------------------------------------------------------
// Scan body — round-7 structure with the Kd-poll + scalar epilogue moved
// from P3 (serialized after the MPs poll) to an idle P2 thread (t=320),
// overlapping it with the E-weight computation.  P2 skips writing index
// i-1 so the concurrent scalar append is race-free.
// ---------------------------------------------------------------------------
template<int ISL2>
__device__ void scan_body(
    ScanSm* S, int b, int w, int t,
    const float* __restrict__ xin, float* __restrict__ hout,
    const float* __restrict__ PREg, const float* __restrict__ adj,
    const float* __restrict__ smask,
    const uint32_t* __restrict__ W4l, const uint32_t* __restrict__ Wr4l,
    const float* __restrict__ gbxl, const float* __restrict__ gatwl,
    uint32_t* __restrict__ Hw, u64* __restrict__ MPsl, u64* __restrict__ Kdl,
    u64* __restrict__ HcW, const u64* __restrict__ HcR,
    const u64* __restrict__ PREcR,
    float* __restrict__ AsB, int sbase)
{
    const int lane = t & 63, wave = t >> 6;
    const int dg0 = w * DS;
    const float* adjB = adj   + (size_t)b * N_ * N_;
    const float* smB  = smask + (size_t)b * N_ * N_;
    const int fi = b * NW;
    const int cB4 = t >> 1, khB4 = t & 1;
    const int w1 = (w + 1) & 3, w2 = (w + 2) & 3, w3 = (w + 3) & 3;

    // Wr -> LDS; Gc weights -> registers
    {
        uint32_t* wr = (uint32_t*)S->Wr4s;
        for (int q = t; q < 9216; q += 576) wr[q] = Wr4l[q];
    }
    uint4 wreg[12];
    {
        const uint4* W4v = (const uint4*)W4l;
        #pragma unroll
        for (int p4 = 0; p4 < 12; ++p4) wreg[p4] = W4v[(12 * khB4 + p4) * GC + cB4];
    }
    float wkv = 0.f, g2b = 0.f, g5b = 0.f;
    if (t < DS) { wkv = gatwl[DH_ + dg0 + t]; g2b = gbxl[dg0 + t]; g5b = gbxl[DH_ + dg0 + t]; }
    if (t < N_) { S->sKsc[t] = 0.f; S->sA0[1][t] = 0.f; S->sA1[1][t] = 0.f; }
    if (t < DS) { S->su0[t] = 0.f; S->su1[t] = 0.f; }
    if (t < 8)  S->sRedS[1][t] = 0.f;
    if (w == 0 && t < N_) AsB[t] = 0.f;

    if (!ISL2) {
        if (t < DS) {
            const float* pre = PREg + (size_t)(b * N_) * G6 + dg0 + t;
            S->sPre[t] = pre[0]; S->sPre[DS + t] = pre[192]; S->sPre[2 * DS + t] = pre[384];
            S->sPre[3 * DS + t] = pre[576]; S->sPre[4 * DS + t] = pre[768]; S->sPre[5 * DS + t] = pre[960];
            S->sXv[t] = xin[(size_t)(b * N_) * G3 + dg0 + t];
        }
        for (int q = t; q < 128; q += 576) {
            if (q < 64)  *(float4*)&S->sAdjN[4 * q] = *(const float4*)(adjB + N_ + 4 * q);
            else { int q2 = q - 64; *(float4*)&S->sSmN[4 * q2] = *(const float4*)(smB + N_ + 4 * q2); }
        }
    } else {
        for (int q = t; q < 320; q += 576) {
            if (q < 64)       *(float4*)&S->sAdjN[4 * q] = *(const float4*)(adjB + N_ + 4 * q);
            else if (q < 128) { int q2 = q - 64;  *(float4*)&S->sSmN[4 * q2] = *(const float4*)(smB + N_ + 4 * q2); }
            else if (q < 176) {
                int d = q - 128;
                const u64* p = HcR + ((size_t)(b * N_) * NW + w) * DS + d;
                u64 v; do { v = agload(p); } while ((uint32_t)(v >> 32) != (uint32_t)STH);
                S->sXv[d] = __uint_as_float((uint32_t)v);
            } else {
                int qq = q - 176;
                const u64* p = PREcR + ((size_t)(b * N_) * NW + w) * 144 + qq;
                u64 v; do { v = agload(p); } while ((uint32_t)(v >> 32) != (uint32_t)STP);
                uint32_t pl = (uint32_t)v;
                S->sPre[2 * qq] = bflo(pl); S->sPre[2 * qq + 1] = bfhi(pl);
            }
        }
    }
    __syncthreads();
    // ---- step 0 (no attention) ----
    {
        float hn = 0.f;
        if (t < DS) {
            float xv = S->sXv[t];
            float r1 = sigm(S->sPre[t]), z1 = sigm(S->sPre[DS + t]);
            float n1 = tanhf_(S->sPre[2 * DS + t] + r1 * g2b);
            float Cv = (1.f - z1) * n1;
            float r2 = sigm(S->sPre[3 * DS + t]), z2 = sigm(S->sPre[4 * DS + t]);
            float n2 = tanhf_(g5b + r2 * S->sPre[5 * DS + t]);
            hn = Cv + (1.f - z2) * n2 + z2 * xv;
            S->sHn[t] = hn;
            hout[(size_t)(b * N_) * G3 + dg0 + t] = hn;
            if (!ISL2) HcW[((size_t)(b * N_) * NW + w) * DS + t] = packvs(hn, STH);
        }
        if (t == 0) { S->sSavedA[1] = S->sAdjN[0]; S->sSavedS[1] = S->sSmN[0]; }
        if (wave == 0) {
            float v = hn * wkv;
            #pragma unroll
            for (int o = 32; o; o >>= 1) v += __shfl_xor(v, o);
            if (lane == 0) { S->sSaved[6] = v; agstore(&Kdl[fi + w], packvs(v, sbase)); }  // parity 0
        }
    }
    __syncthreads();
    if (t < KD) Hw[(size_t)t * N_] = f2bf(S->sHn[2 * t]) | (f2bf(S->sHn[2 * t + 1]) << 16);
    __syncthreads();

    for (int i = 1; i < N_; ++i) {
        const int row = b * N_ + i;
        const int stamp = sbase + i;
        const int pp = i & 1, pn = pp ^ 1;

        // ---- P1: raw partials + stamped send; prefetch ----------------------
        if (t < DH_) {
            float rr = 0.f, p0 = 0.f, p1 = 0.f;
            #pragma unroll 4
            for (int kq = 0; kq < 12; ++kq) {
                uint4 wv = S->Wr4s[kq * DH_ + t];
                const int k0 = 4 * kq;
                float lo, hi;
                lo = bflo(wv.x); hi = bfhi(wv.x);
                rr = fmaf(S->su0[k0 + 0], lo, rr); rr = fmaf(S->su1[k0 + 0], hi, rr);
                p0 = fmaf(S->sHn[k0 + 0], lo, p0); p1 = fmaf(S->sHn[k0 + 0], hi, p1);
                lo = bflo(wv.y); hi = bfhi(wv.y);
                rr = fmaf(S->su0[k0 + 1], lo, rr); rr = fmaf(S->su1[k0 + 1], hi, rr);
                p0 = fmaf(S->sHn[k0 + 1], lo, p0); p1 = fmaf(S->sHn[k0 + 1], hi, p1);
                lo = bflo(wv.z); hi = bfhi(wv.z);
                rr = fmaf(S->su0[k0 + 2], lo, rr); rr = fmaf(S->su1[k0 + 2], hi, rr);
                p0 = fmaf(S->sHn[k0 + 2], lo, p0); p1 = fmaf(S->sHn[k0 + 2], hi, p1);
                lo = bflo(wv.w); hi = bfhi(wv.w);
                rr = fmaf(S->su0[k0 + 3], lo, rr); rr = fmaf(S->su1[k0 + 3], hi, rr);
                p0 = fmaf(S->sHn[k0 + 3], lo, p0); p1 = fmaf(S->sHn[k0 + 3], hi, p1);
            }
            S->sRl[t] = rr; S->sP0l[t] = p0; S->sP1l[t] = p1;
            u64* base = &MPsl[(size_t)pp * MPSZ + ((size_t)(fi + w) * DH_ + t) * 3];
            agstore(base + 0, packvs(rr, stamp));
            agstore(base + 1, packvs(p0, stamp));
            agstore(base + 2, packvs(p1, stamp));
        } else if (t >= 384) {
            const int u = t - 384;
            const int inx = (i + 1 < N_) ? i + 1 : N_ - 1;
            if (!ISL2) {
                for (int qq = u; qq < 212; qq += 192) {
                    if (qq < 64)
                        *(float4*)&S->sAdjN[4 * qq] = *(const float4*)(adjB + (size_t)inx * N_ + 4 * qq);
                    else if (qq < 128) { int q2 = qq - 64;
                        *(float4*)&S->sSmN[4 * q2] = *(const float4*)(smB + (size_t)inx * N_ + 4 * q2); }
                    else if (qq < 140) { int q2 = qq - 128;
                        *(float4*)&S->sXv[4 * q2] = *(const float4*)(xin + (size_t)row * G3 + dg0 + 4 * q2); }
                    else { int q2 = qq - 140; int g = q2 / 12, o = q2 - 12 * g;
                        *(float4*)&S->sPre[g * DS + 4 * o] =
                            *(const float4*)(PREg + (size_t)row * G6 + g * DH_ + dg0 + 4 * o); }
                }
            } else {
                for (int qq = u; qq < 320; qq += 192) {
                    if (qq < 64)
                        *(float4*)&S->sAdjN[4 * qq] = *(const float4*)(adjB + (size_t)inx * N_ + 4 * qq);
                    else if (qq < 128) { int q2 = qq - 64;
                        *(float4*)&S->sSmN[4 * q2] = *(const float4*)(smB + (size_t)inx * N_ + 4 * q2); }
                    else if (qq < 176) {
                        int d = qq - 128;
                        const u64* p = HcR + ((size_t)row * NW + w) * DS + d;
                        u64 v; do { v = agload(p); } while ((uint32_t)(v >> 32) != (uint32_t)(STH + i));
                        S->sXv[d] = __uint_as_float((uint32_t)v);
                    } else {
                        int q2 = qq - 176;
                        const u64* p = PREcR + ((size_t)row * NW + w) * 144 + q2;
                        u64 v; do { v = agload(p); } while ((uint32_t)(v >> 32) != (uint32_t)(STP + i));
                        uint32_t pl = (uint32_t)v;
                        S->sPre[2 * q2] = bflo(pl); S->sPre[2 * q2 + 1] = bfhi(pl);
                    }
                }
            }
        }
        wg_barrier();                                            // B1

        // ---- P2: E(i+1) weights (t<256, skipping i-1) || Kd poll+scalars ----
        if (t < N_) {
            float e = 0.f;
            if (t == i) { S->sSavedA[pn] = S->sAdjN[t]; S->sSavedS[pn] = S->sSmN[t]; }
            if (t < i - 1 && S->sAdjN[t] > 0.5f) e = __expf(S->sKsc[t]);
            if (t != i - 1) { S->sA0[pn][t] = e * S->sSmN[t]; S->sA1[pn][t] = e - e * S->sSmN[t]; }
            float ps = e;
            #pragma unroll
            for (int o = 32; o; o >>= 1) ps += __shfl_xor(ps, o);
            if (lane == 0) S->sRedS[pn][wave] = ps;
        } else if (t == 320) {
            const uint32_t ex2 = (uint32_t)(stamp - 1);
            const int kpar = (i - 1) & 1;
            u64 k0, k1, k2;
            u64* q1 = &Kdl[kpar * KDSZ + fi + w1];
            u64* q2 = &Kdl[kpar * KDSZ + fi + w2];
            u64* q3 = &Kdl[kpar * KDSZ + fi + w3];
            do {
                k0 = agload(q1); k1 = agload(q2); k2 = agload(q3);
            } while ((uint32_t)(k0 >> 32) != ex2 || (uint32_t)(k1 >> 32) != ex2 ||
                     (uint32_t)(k2 >> 32) != ex2);
            float kdot = S->sSaved[6] + u2f(k0) + u2f(k1) + u2f(k2);
            float adj1 = S->sSavedA[pp], sm1 = S->sSavedS[pp];
            float er = __expf(kdot);
            float e1 = (adj1 > 0.5f) ? er : 0.f;
            float Ssum = S->sRedS[pp][0] + S->sRedS[pp][1] + S->sRedS[pp][2]
                       + S->sRedS[pp][3] + S->sRedS[pp][4] + e1;
            S->sKsc[i - 1] = kdot;
            float invS = 1.f / Ssum;
            float e1c0 = e1 * sm1, e1c1 = e1 - e1c0;
            S->sSaved[2] = invS;
            S->sSaved[4] = e1c0; S->sSaved[5] = e1c1;
            S->sA0[pp][i - 1] = e1c0; S->sA1[pp][i - 1] = e1c1;
            // append j = i-1 term for query i+1 (sAdjN holds row i+1 now)
            float adjn = S->sAdjN[i - 1], smn = S->sSmN[i - 1];
            float en = (adjn > 0.5f) ? er : 0.f;
            float n0 = en * smn;
            S->sA0[pn][i - 1] = n0; S->sA1[pn][i - 1] = en - n0;
            S->sRedS[pn][4] = en;
        }
        wg_barrier();                                            // B2

        // ---- P3: U(i+1) matvec || stamped 9-addr MPs poll -------------------
        if (t < 384) {
            const int ilim = i - 1;                              // j <= i-2
            const int kd = t >> 4, jp = t & 15;
            const uint32_t* hp = Hw + (size_t)kd * N_;
            float u0l = 0.f, u0h = 0.f, u1l = 0.f, u1h = 0.f;
            int j = jp;
            while (j + 48 < ilim) {
                uint32_t h0 = hp[j], h1 = hp[j + 16], h2 = hp[j + 32], h3 = hp[j + 48];
                float b0, b1;
                b0 = S->sA0[pn][j];      b1 = S->sA1[pn][j];
                u0l = fmaf(b0, bflo(h0), u0l); u0h = fmaf(b0, bfhi(h0), u0h);
                u1l = fmaf(b1, bflo(h0), u1l); u1h = fmaf(b1, bfhi(h0), u1h);
                b0 = S->sA0[pn][j + 16]; b1 = S->sA1[pn][j + 16];
                u0l = fmaf(b0, bflo(h1), u0l); u0h = fmaf(b0, bfhi(h1), u0h);
                u1l = fmaf(b1, bflo(h1), u1l); u1h = fmaf(b1, bfhi(h1), u1h);
                b0 = S->sA0[pn][j + 32]; b1 = S->sA1[pn][j + 32];
                u0l = fmaf(b0, bflo(h2), u0l); u0h = fmaf(b0, bfhi(h2), u0h);
                u1l = fmaf(b1, bflo(h2), u1l); u1h = fmaf(b1, bfhi(h2), u1h);
                b0 = S->sA0[pn][j + 48]; b1 = S->sA1[pn][j + 48];
                u0l = fmaf(b0, bflo(h3), u0l); u0h = fmaf(b0, bfhi(h3), u0h);
                u1l = fmaf(b1, bflo(h3), u1l); u1h = fmaf(b1, bfhi(h3), u1h);
                j += 64;
            }
            for (; j < ilim; j += 16) {
                uint32_t hv = hp[j];
                float b0 = S->sA0[pn][j], b1 = S->sA1[pn][j];
                u0l = fmaf(b0, bflo(hv), u0l); u0h = fmaf(b0, bfhi(hv), u0h);
                u1l = fmaf(b1, bflo(hv), u1l); u1h = fmaf(b1, bfhi(hv), u1h);
            }
            #pragma unroll
            for (int o = 1; o <= 8; o <<= 1) {
                u0l += __shfl_xor(u0l, o); u0h += __shfl_xor(u0h, o);
                u1l += __shfl_xor(u1l, o); u1h += __shfl_xor(u1h, o);
            }
            if (jp == 0) {
                S->su0[2 * kd] = u0l; S->su0[2 * kd + 1] = u0h;
                S->su1[2 * kd] = u1l; S->su1[2 * kd + 1] = u1h;
            }
        } else {
            const int d = t - 384;
            const u64* pA = &MPsl[(size_t)pp * MPSZ + ((size_t)(fi + w1) * DH_ + d) * 3];
            const u64* pB = &MPsl[(size_t)pp * MPSZ + ((size_t)(fi + w2) * DH_ + d) * 3];
            const u64* pC = &MPsl[(size_t)pp * MPSZ + ((size_t)(fi + w3) * DH_ + d) * 3];
            const uint32_t ex = (uint32_t)stamp;
            u64 a0, a1, a2, b0, b1, b2, c0, c1, c2;
            do {
                a0 = agload(pA); a1 = agload(pA + 1); a2 = agload(pA + 2);
                b0 = agload(pB); b1 = agload(pB + 1); b2 = agload(pB + 2);
                c0 = agload(pC); c1 = agload(pC + 1); c2 = agload(pC + 2);
            } while ((uint32_t)(a0 >> 32) != ex || (uint32_t)(a1 >> 32) != ex ||
                     (uint32_t)(a2 >> 32) != ex || (uint32_t)(b0 >> 32) != ex ||
                     (uint32_t)(b1 >> 32) != ex || (uint32_t)(b2 >> 32) != ex ||
                     (uint32_t)(c0 >> 32) != ex || (uint32_t)(c1 >> 32) != ex ||
                     (uint32_t)(c2 >> 32) != ex);
            S->sRl[d]  += u2f(a0) + u2f(b0) + u2f(c0);
            S->sP0l[d] += u2f(a1) + u2f(b1) + u2f(c1);
            S->sP1l[d] += u2f(a2) + u2f(b2) + u2f(c2);
        }
        wg_barrier();                                            // B3

        // ---- P4: final M combine; su append; AsB row i ----------------------
        if (t < DH_) {
            S->sM[t] = (S->sRl[t] + S->sSaved[4] * S->sP0l[t]
                                  + S->sSaved[5] * S->sP1l[t]) * S->sSaved[2];
        } else if (t < 192 + DS) {
            const int k = t - 192;
            float a0 = S->sA0[pn][i - 1], a1 = S->sA1[pn][i - 1];
            S->su0[k] += a0 * S->sHn[k];
            S->su1[k] += a1 * S->sHn[k];
        } else if (w == 0 && t >= 256 && t < 512) {
            const int j = t - 256;
            AsB[(size_t)i * N_ + j] = (S->sA0[pp][j] + S->sA1[pp][j]) * S->sSaved[2];
        }
        wg_barrier();                                            // B4

        // ---- P5: Gc from register-resident weights --------------------------
        {
            float g = 0.f;
            #pragma unroll
            for (int p4 = 0; p4 < 12; ++p4) {
                const uint4 wv = wreg[p4];
                const int m0 = 8 * (12 * khB4 + p4);
                g = fmaf(S->sM[m0 + 0], bflo(wv.x), g); g = fmaf(S->sM[m0 + 1], bfhi(wv.x), g);
                g = fmaf(S->sM[m0 + 2], bflo(wv.y), g); g = fmaf(S->sM[m0 + 3], bfhi(wv.y), g);
                g = fmaf(S->sM[m0 + 4], bflo(wv.z), g); g = fmaf(S->sM[m0 + 5], bfhi(wv.z), g);
                g = fmaf(S->sM[m0 + 6], bflo(wv.w), g); g = fmaf(S->sM[m0 + 7], bfhi(wv.w), g);
            }
            g += __shfl_xor(g, 1);
            if (khB4 == 0) S->sGc[cB4] = g;
        }
        wg_barrier();                                            // B5

        // ---- P6: gates -> hn(i); Hc store; Kd stamped store; Hw pack --------
        {
            float hn = 0.f;
            if (t < DS) {
                float Mv = S->sM[dg0 + t];
                float r1 = sigm(S->sPre[t] + S->sGc[t]);
                float z1 = sigm(S->sPre[DS + t] + S->sGc[DS + t]);
                float n1 = tanhf_(S->sPre[2 * DS + t] + r1 * (S->sGc[2 * DS + t] + g2b));
                float Cv = (1.f - z1) * n1 + z1 * Mv;
                float r2 = sigm(S->sGc[3 * DS + t] + S->sPre[3 * DS + t]);
                float z2 = sigm(S->sGc[4 * DS + t] + S->sPre[4 * DS + t]);
                float n2 = tanhf_(S->sGc[5 * DS + t] + g5b + r2 * S->sPre[5 * DS + t]);
                hn = Cv + (1.f - z2) * n2 + z2 * S->sXv[t];
                S->sHn[t] = hn;
                hout[(size_t)row * G3 + dg0 + t] = hn;
                if (!ISL2) HcW[((size_t)row * NW + w) * DS + t] = packvs(hn, STH + i);
            }
            if (wave == 0) {
                float v = hn * wkv;
                #pragma unroll
                for (int o = 32; o; o >>= 1) v += __shfl_xor(v, o);
                if (lane == 0) { S->sSaved[6] = v; agstore(&Kdl[pp * KDSZ + fi + w], packvs(v, stamp)); }
            }
            if (t < KD) Hw[(size_t)t * N_ + i] = f2bf(S->sHn[2 * t]) | (f2bf(S->sHn[2 * t + 1]) << 16);
        }
        wg_barrier();                                            // B6
    }
}

// ---------------------------------------------------------------------------
// PRE worker — identical to round 7.
// ---------------------------------------------------------------------------
__device__ void worker_body(WorkSm* Wm, int b, int w, int t,
    const uint32_t* __restrict__ Wp4g, const float* __restrict__ bias2,
    const u64* __restrict__ HcR, u64* __restrict__ PREcW)
{
    const int c = t >> 1, kh = t & 1;
    uint4 wpreg[12];
    {
        const uint4* v4 = (const uint4*)Wp4g;
        #pragma unroll
        for (int p4 = 0; p4 < 12; ++p4) wpreg[p4] = v4[(12 * kh + p4) * GC + c];
    }
    float bv = 0.f;
    if (kh == 0) bv = bias2[192 * (c / DS) + w * DS + (c % DS)];
    for (int i = 0; i < N_; ++i) {
        if (t < DH_) {
            const u64* p = HcR + ((size_t)(b * N_ + i) * NW + (t / DS)) * DS + (t % DS);
            u64 v; do { v = agload(p); } while ((uint32_t)(v >> 32) != (uint32_t)(STH + i));
            Wm->sX[t] = __uint_as_float((uint32_t)v);
        }
        wg_barrier();
        {
            float g = 0.f;
            #pragma unroll
            for (int p4 = 0; p4 < 12; ++p4) {
                const uint4 wv = wpreg[p4];
                const int m0 = 8 * (12 * kh + p4);
                g = fmaf(Wm->sX[m0 + 0], bflo(wv.x), g); g = fmaf(Wm->sX[m0 + 1], bfhi(wv.x), g);
                g = fmaf(Wm->sX[m0 + 2], bflo(wv.y), g); g = fmaf(Wm->sX[m0 + 3], bfhi(wv.y), g);
                g = fmaf(Wm->sX[m0 + 4], bflo(wv.z), g); g = fmaf(Wm->sX[m0 + 5], bfhi(wv.z), g);
                g = fmaf(Wm->sX[m0 + 6], bflo(wv.w), g); g = fmaf(Wm->sX[m0 + 7], bfhi(wv.w), g);
            }
            g += __shfl_xor(g, 1);
            if (kh == 0) Wm->sPv[c] = g + bv;
        }
        wg_barrier();
        if (t < 144) {
            u64 v = ((u64)(uint32_t)(STP + i) << 32)
                  | f2bf(Wm->sPv[2 * t]) | (f2bf(Wm->sPv[2 * t + 1]) << 16);
            agstore(&PREcW[((size_t)(b * N_ + i) * NW + w) * 144 + t], v);
        }
        wg_barrier();
    }
}

// ---------------------------------------------------------------------------
// Single fused kernel.
// ---------------------------------------------------------------------------
__global__ __launch_bounds__(576, 1) void pipeline_kernel(
    const float* __restrict__ features, const float* __restrict__ fc1_w,
    const float* __restrict__ fc1_b,
    const float* __restrict__ adj, const float* __restrict__ smask,
    const float* __restrict__ gatw,
    const float* __restrict__ wr0, const float* __restrict__ wr1,
    const float* __restrict__ c_wih, const float* __restrict__ c_whh,
    const float* __restrict__ c_bih, const float* __restrict__ c_bhh,
    const float* __restrict__ p_wih, const float* __restrict__ p_whh,
    const float* __restrict__ p_bih, const float* __restrict__ p_bhh,
    const float* __restrict__ mw0, const float* __restrict__ mb0,
    const float* __restrict__ mw1, const float* __restrict__ mb1,
    const float* __restrict__ mw2, const float* __restrict__ mb2,
    float* __restrict__ Hcat, float* __restrict__ PREg,
    float* __restrict__ WpreT, uint32_t* __restrict__ W4,
    uint32_t* __restrict__ Wr4, uint32_t* __restrict__ Wp4w,
    float* __restrict__ biasPre, float* __restrict__ gbx,
    uint32_t* __restrict__ Hb, u64* __restrict__ MPs, u64* __restrict__ Kd,
    u64* __restrict__ Hc, u64* __restrict__ PREc,
    u64* __restrict__ Fp, u64* __restrict__ Fd,
    float* __restrict__ out)
{
    __shared__ __align__(16) char smem[sizeof(SmemAll)];
    const int blk = blockIdx.x, t = threadIdx.x;
    const int wgid = blk;
    const int b = blk & 7, r12 = blk >> 3;
    const int role = r12 >> 2, w = r12 & 3;

    // ---- prepack slices (all WGs) ------------------------------------------
    for (int j = 0; j < 4; ++j) {
        int idx = wgid * 576 + t + 55296 * j;
        prepack_slice(idx, wr0, wr1, c_wih, c_whh, c_bih, c_bhh,
                      p_wih, p_whh, p_bih, p_bhh,
                      WpreT, W4, Wr4, Wp4w, biasPre, gbx);
    }
    flag_sync(Fp, wgid, t, SPK);

    // ---- fc1 + PRE-l1 prologue ---------------------------------------------
    prologue(smem, wgid, t, features, fc1_w, fc1_b, WpreT, biasPre,
             Hcat, PREg, Fp);

    // ---- roles -------------------------------------------------------------
    float* As = out + 393216;
    if (role == 0) {
        scan_body<0>((ScanSm*)smem, b, w, t,
            Hcat, Hcat + 192, PREg, adj, smask,
            W4, Wr4, gbx, gatw,
            Hb + (size_t)(b * NW + w) * KD * N_, MPs, Kd,
            Hc, nullptr, nullptr,
            As + (size_t)b * (L_ * N_ * N_), 1);
        __threadfence();
        __syncthreads();
        if (t == 0) agstore(&Fd[b * 8 + w], packvs(0.f, SDN));
    } else if (role == 2) {
        scan_body<1>((ScanSm*)smem, b, w, t,
            nullptr, Hcat + 384, nullptr, adj, smask,
            W4 + NW * 27648, Wr4 + NW * 9216, gbx + 384, gatw + 384,
            Hb + (size_t)(32 + b * NW + w) * KD * N_,
            MPs + (size_t)2 * MPSZ, Kd + 2 * KDSZ,
            nullptr, Hc, PREc,
            As + (size_t)b * (L_ * N_ * N_) + N_ * N_, 30001);
        __threadfence();
        __syncthreads();
        if (t == 0) agstore(&Fd[b * 8 + 4 + w], packvs(0.f, SDN));
    } else {
        worker_body((WorkSm*)smem, b, w, t,
            Wp4w + (size_t)w * 27648, biasPre + G6,
            Hc, PREc);
    }

    // ---- MLP epilogue (all WGs) --------------------------------------------
    mlp_tail(smem, wgid, t, Hcat, mw0, mb0, mw1, mb1, mw2, mb2, out, Fd);
}

// ---------------------------------------------------------------------------
extern "C" void kernel_launch(void* const* d_in, const int* in_sizes, int n_in,
                              void* d_out, int out_size, void* d_ws, size_t ws_size,
                              hipStream_t stream)
{
    const float* features = (const float*)d_in[0];
    const float* adj      = (const float*)d_in[1];
    const float* smask    = (const float*)d_in[2];
    const float* fc1_w = (const float*)d_in[5];
    const float* fc1_b = (const float*)d_in[6];
    const float* gat_w = (const float*)d_in[7];
    const float* wr0   = (const float*)d_in[9];
    const float* wr1   = (const float*)d_in[10];
    const float* c_wih = (const float*)d_in[11];
    const float* c_whh = (const float*)d_in[12];
    const float* c_bih = (const float*)d_in[13];
    const float* c_bhh = (const float*)d_in[14];
    const float* p_wih = (const float*)d_in[15];
    const float* p_whh = (const float*)d_in[16];
    const float* p_bih = (const float*)d_in[17];
    const float* p_bhh = (const float*)d_in[18];
    const float* mw0 = (const float*)d_in[19];
    const float* mb0 = (const float*)d_in[20];
    const float* mw1 = (const float*)d_in[21];
    const float* mb1 = (const float*)d_in[22];
    const float* mw2 = (const float*)d_in[23];
    const float* mb2 = (const float*)d_in[24];
    float* out = (float*)d_out;

    char* wsb = (char*)d_ws;
    size_t off = 0;
    auto carve = [&](size_t bytes) -> char* {
        char* p = wsb + off;
        off = (off + bytes + 255) & ~(size_t)255;
        return p;
    };
    float* Hcat     = (float*)carve(2048ull * 576 * 4);
    float* PREg     = (float*)carve(2048ull * 1152 * 4);
    float* WpreT    = (float*)carve(192ull * 1152 * 4);
    uint32_t* W4    = (uint32_t*)carve(2ull * NW * 27648 * 4);
    uint32_t* Wr4   = (uint32_t*)carve(2ull * NW * 9216 * 4);
    uint32_t* Wp4w  = (uint32_t*)carve((size_t)NW * 27648 * 4);
    float* biasPre  = (float*)carve(2ull * 1152 * 4);
    float* gbx      = (float*)carve(2ull * 384 * 4);
    uint32_t* Hb    = (uint32_t*)carve(64ull * KD * 256 * 4);
    u64* MPs        = (u64*)carve(4ull * MPSZ * 8);      // 2 roles x 2 parities
    u64* Kd         = (u64*)carve(4ull * KDSZ * 8);      // 2 roles x 2 parities
    u64* Hc         = (u64*)carve(8ull * 256 * NW * DS * 8);
    u64* PREc       = (u64*)carve(8ull * 256 * NW * 144 * 8);
    u64* Fp         = (u64*)carve(288ull * 8);
    u64* Fd         = (u64*)carve(64ull * 8);

    pipeline_kernel<<<dim3(96), 576, 0, stream>>>(
        features, fc1_w, fc1_b, adj, smask, gat_w,
        wr0, wr1, c_wih, c_whh, c_bih, c_bhh, p_wih, p_whh, p_bih, p_bhh,
        mw0, mb0, mw1, mb1, mw2, mb2,
        Hcat, PREg, WpreT, W4, Wr4, Wp4w, biasPre, gbx,
        Hb, MPs, Kd, Hc, PREc, Fp, Fd, out);
}